// Round 5
// baseline (932.595 us; speedup 1.0000x reference)
//
#include <hip/hip_runtime.h>

typedef float v2f __attribute__((ext_vector_type(2)));

#define NBATCH 131072
#define NSTEPS 499

template<int CTRL>
__device__ __forceinline__ float dppmov(float x) {
    int i = __builtin_amdgcn_mov_dpp(__float_as_int(x), CTRL, 0xF, 0xF, true);
    return __int_as_float(i);
}

__global__ __launch_bounds__(256, 4) void ode_euler_kernel(
    const float* __restrict__ y0,
    const float* __restrict__ t,
    const float* __restrict__ w1,
    const float* __restrict__ b1,
    const float* __restrict__ w2,
    const float* __restrict__ b2,
    float* __restrict__ out)
{
    const int tid = threadIdx.x;
    const int gtid = blockIdx.x * 256 + tid;
    const int sub = gtid & 3;      // 4 lanes cooperate on one element
    const int e = gtid >> 2;       // element index

    // t is linspace(0,25,500): dt constant to 1 ulp. Uniform -> lives in SGPRs.
    const float dt = (t[NSTEPS] - t[0]) * (1.0f / (float)NSTEPS);

    // hidden-unit pair range: sub0 -> pairs 0..6 (7), sub1 -> 7..12, sub2 -> 13..18, sub3 -> 19..24
    const int start = (sub == 0) ? 0 : (1 + 6 * sub);
    const int count = (sub == 0) ? 7 : 6;

    const float S = 2.8853900817779268f;  // 2*log2(e):  tanh(a) = 1 - 2/(1 + 2^(S*a))

    // Weights folded: pv = S*(w1.y + b1); dy = c + sum(-2*w2 * 1/(1+2^pv))
    v2f wxv[7], wyv[7], bsv[7], m0v[7], m1v[7];
    #pragma unroll
    for (int q = 0; q < 7; ++q) {
        if (q < count) {
            const int p = start + q;
            const int u0 = 2 * p, u1 = 2 * p + 1;
            wxv[q] = (v2f){S * w1[2 * u0 + 0], S * w1[2 * u1 + 0]};
            wyv[q] = (v2f){S * w1[2 * u0 + 1], S * w1[2 * u1 + 1]};
            bsv[q] = (v2f){S * b1[u0], S * b1[u1]};
            m0v[q] = (v2f){-2.0f * w2[u0], -2.0f * w2[u1]};
            m1v[q] = (v2f){-2.0f * w2[50 + u0], -2.0f * w2[50 + u1]};
        } else {  // padded pair: pv=0 -> r=0.5, m=0 -> contributes 0
            wxv[q] = (v2f){0.f, 0.f}; wyv[q] = (v2f){0.f, 0.f}; bsv[q] = (v2f){0.f, 0.f};
            m0v[q] = (v2f){0.f, 0.f}; m1v[q] = (v2f){0.f, 0.f};
        }
    }
    // c = b2 + sum(w2) distributed: each thread carries w2-sum of ITS units (= -0.5*sum(m)),
    // b2 only on sub0; the per-step butterfly reduction completes the total.
    float cc0 = (sub == 0) ? b2[0] : 0.0f;
    float cc1 = (sub == 0) ? b2[1] : 0.0f;
    #pragma unroll
    for (int q = 0; q < 7; ++q) {
        cc0 -= 0.5f * (m0v[q].x + m0v[q].y);
        cc1 -= 0.5f * (m1v[q].x + m1v[q].y);
    }

    v2f y = ((const v2f*)y0)[e];
    v2f* outv = (v2f*)out;
    if (sub == 0) __builtin_nontemporal_store(y, outv + e);   // out[0] = y0
    v2f* po = outv + NBATCH + e;

    for (int k = 0; k < NSTEPS; ++k) {
        v2f a0 = {cc0, 0.0f};
        v2f a1 = {cc1, 0.0f};
        const v2f ysx = {y.x, y.x};
        const v2f ysy = {y.y, y.y};
        #pragma unroll
        for (int q = 0; q < 7; ++q) {
            v2f pv = wxv[q] * ysx + (wyv[q] * ysy + bsv[q]);
            pv.x = fminf(pv.x, 88.0f);   // keep 2^pv finite: Newton-rcp can't eat inf
            pv.y = fminf(pv.y, 88.0f);
            v2f ev;
            ev.x = __builtin_amdgcn_exp2f(pv.x);
            ev.y = __builtin_amdgcn_exp2f(pv.y);
            v2f d = ev + 1.0f;
            // r = 1/d: bit-trick seed + 2 packed-Newton iterations (pure VALU, no trans)
            unsigned ux = 0x7EF311C3u - __float_as_uint(d.x);
            unsigned uy = 0x7EF311C3u - __float_as_uint(d.y);
            v2f r = {__uint_as_float(ux), __uint_as_float(uy)};
            r = r * (2.0f - d * r);
            r = r * (2.0f - d * r);
            a0 += m0v[q] * r;
            a1 += m1v[q] * r;
        }
        // horizontal + butterfly across the 4 cooperating lanes (DPP quad_perm, pure VALU)
        v2f g = {a0.x + a0.y, a1.x + a1.y};
        v2f gs;
        gs.x = dppmov<0xB1>(g.x); gs.y = dppmov<0xB1>(g.y);  // xor 1
        g += gs;
        gs.x = dppmov<0x4E>(g.x); gs.y = dppmov<0x4E>(g.y);  // xor 2
        g += gs;
        const v2f dtv = {dt, dt};
        y += dtv * g;
        if (sub == 0) __builtin_nontemporal_store(y, po);
        po += NBATCH;
    }
}

extern "C" void kernel_launch(void* const* d_in, const int* in_sizes, int n_in,
                              void* d_out, int out_size, void* d_ws, size_t ws_size,
                              hipStream_t stream) {
    const float* y0 = (const float*)d_in[0];
    const float* t  = (const float*)d_in[1];
    const float* w1 = (const float*)d_in[2];
    const float* b1 = (const float*)d_in[3];
    const float* w2 = (const float*)d_in[4];
    const float* b2 = (const float*)d_in[5];
    float* out = (float*)d_out;
    ode_euler_kernel<<<(NBATCH * 4) / 256, 256, 0, stream>>>(y0, t, w1, b1, w2, b2, out);
}

// Round 7
// 750.194 us; speedup vs baseline: 1.2431x; 1.2431x over previous
//
#include <hip/hip_runtime.h>

typedef float v2f __attribute__((ext_vector_type(2)));

#define NBATCH 131072
#define NSTEPS 499

template<int CTRL>
__device__ __forceinline__ float dppmov(float x) {
    int i = __builtin_amdgcn_mov_dpp(__float_as_int(x), CTRL, 0xF, 0xF, true);
    return __int_as_float(i);
}

// Packed fp32 FMA (VOP3P, gfx90a+). Early-clobber output: the destination pair
// can never alias an input pair, removing any regalloc aliasing edge case.
__device__ __forceinline__ v2f pkfma(v2f a, v2f b, v2f c) {
    v2f d;
    asm("v_pk_fma_f32 %0, %1, %2, %3" : "=&v"(d) : "v"(a), "v"(b), "v"(c));
    return d;
}

__global__ __launch_bounds__(256, 4) void ode_euler_kernel(
    const float* __restrict__ y0,
    const float* __restrict__ t,
    const float* __restrict__ w1,
    const float* __restrict__ b1,
    const float* __restrict__ w2,
    const float* __restrict__ b2,
    float* __restrict__ out)
{
    const int tid = threadIdx.x;
    const int gtid = blockIdx.x * 256 + tid;
    const int sub = gtid & 3;      // 4 lanes cooperate on one element
    const int e = gtid >> 2;       // element index

    // t is linspace(0,25,500): dt constant to 1 ulp. Uniform -> SGPR.
    const float dt = (t[NSTEPS] - t[0]) * (1.0f / (float)NSTEPS);

    // hidden-unit pair range: sub0 -> pairs 0..6 (7), sub1 -> 7..12, sub2 -> 13..18, sub3 -> 19..24
    const int start = (sub == 0) ? 0 : (1 + 6 * sub);
    const int count = (sub == 0) ? 7 : 6;

    const float S = 2.8853900817779268f;  // 2*log2(e):  tanh(a) = 1 - 2/(1 + 2^(S*a))

    // Weights folded: pv = S*(w1.y + b1); dy = c + sum(-2*w2 * 1/(1+2^pv))
    v2f wxv[7], wyv[7], bsv[7], m0v[7], m1v[7];
    #pragma unroll
    for (int q = 0; q < 7; ++q) {
        if (q < count) {
            const int p = start + q;
            const int u0 = 2 * p, u1 = 2 * p + 1;
            wxv[q] = (v2f){S * w1[2 * u0 + 0], S * w1[2 * u1 + 0]};
            wyv[q] = (v2f){S * w1[2 * u0 + 1], S * w1[2 * u1 + 1]};
            bsv[q] = (v2f){S * b1[u0], S * b1[u1]};
            m0v[q] = (v2f){-2.0f * w2[u0], -2.0f * w2[u1]};
            m1v[q] = (v2f){-2.0f * w2[50 + u0], -2.0f * w2[50 + u1]};
        } else {  // padded pair: pv=0 -> r=0.5, m=0 -> contributes 0
            wxv[q] = (v2f){0.f, 0.f}; wyv[q] = (v2f){0.f, 0.f}; bsv[q] = (v2f){0.f, 0.f};
            m0v[q] = (v2f){0.f, 0.f}; m1v[q] = (v2f){0.f, 0.f};
        }
    }
    // c = b2 + sum(w2) distributed: each thread carries w2-sum of ITS units (= -0.5*sum(m)),
    // b2 only on sub0; the per-step butterfly reduction completes the total.
    float cc0 = (sub == 0) ? b2[0] : 0.0f;
    float cc1 = (sub == 0) ? b2[1] : 0.0f;
    #pragma unroll
    for (int q = 0; q < 7; ++q) {
        cc0 -= 0.5f * (m0v[q].x + m0v[q].y);
        cc1 -= 0.5f * (m1v[q].x + m1v[q].y);
    }

    v2f y = ((const v2f*)y0)[e];
    v2f* outv = (v2f*)out;
    if (sub == 0) __builtin_nontemporal_store(y, outv + e);   // out[0] = y0
    v2f* po = outv + NBATCH + e;

    for (int k = 0; k < NSTEPS; ++k) {
        v2f a0 = {cc0, 0.0f};
        v2f a1 = {cc1, 0.0f};
        const v2f ysx = {y.x, y.x};
        const v2f ysy = {y.y, y.y};
        #pragma unroll
        for (int q = 0; q < 7; ++q) {
            v2f pv = wxv[q] * ysx + (wyv[q] * ysy + bsv[q]);   // C, compiler-lowered
            v2f ev;
            ev.x = __builtin_amdgcn_exp2f(pv.x);               // trans
            ev.y = __builtin_amdgcn_exp2f(pv.y);               // trans
            v2f d = ev + 1.0f;                                 // C
            v2f r;
            r.x = __builtin_amdgcn_rcpf(d.x);                  // trans; rcp(inf)=0 saturates
            r.y = __builtin_amdgcn_rcpf(d.y);                  // trans
            a0 = pkfma(m0v[q], r, a0);                         // ASM pk (the experiment)
            a1 = pkfma(m1v[q], r, a1);                         // ASM pk
        }
        // horizontal + butterfly across the 4 cooperating lanes (DPP quad_perm, VALU)
        v2f g = {a0.x + a0.y, a1.x + a1.y};
        v2f gs;
        gs.x = dppmov<0xB1>(g.x); gs.y = dppmov<0xB1>(g.y);  // xor 1
        g += gs;
        gs.x = dppmov<0x4E>(g.x); gs.y = dppmov<0x4E>(g.y);  // xor 2
        g += gs;
        y.x = fmaf(dt, g.x, y.x);
        y.y = fmaf(dt, g.y, y.y);
        if (sub == 0) __builtin_nontemporal_store(y, po);
        po += NBATCH;
    }
}

extern "C" void kernel_launch(void* const* d_in, const int* in_sizes, int n_in,
                              void* d_out, int out_size, void* d_ws, size_t ws_size,
                              hipStream_t stream) {
    const float* y0 = (const float*)d_in[0];
    const float* t  = (const float*)d_in[1];
    const float* w1 = (const float*)d_in[2];
    const float* b1 = (const float*)d_in[3];
    const float* w2 = (const float*)d_in[4];
    const float* b2 = (const float*)d_in[5];
    float* out = (float*)d_out;
    ode_euler_kernel<<<(NBATCH * 4) / 256, 256, 0, stream>>>(y0, t, w1, b1, w2, b2, out);
}